// Round 1
// baseline (517.186 us; speedup 1.0000x reference)
//
#include <hip/hip_runtime.h>
#include <cstdint>
#include <cstddef>

#define NEG_SLOPE 0.2f

static __device__ __forceinline__ float leaky(float x){ return x > 0.f ? x : NEG_SLOPE*x; }
static __device__ __forceinline__ float pick4(float4 v, int h){
  float r = v.x;
  if (h==1) r = v.y;
  if (h==2) r = v.z;
  if (h==3) r = v.w;
  return r;
}

// ---------------- edge index decode (int32 vs int64 runtime detection) ----------------
__global__ __launch_bounds__(256) void k_detect(const unsigned int* __restrict__ w, int E,
                                                int* __restrict__ flag){
  int i = blockIdx.x*256 + threadIdx.x;
  // If data is int64 (values < 2^31), every odd 32-bit word among the first 2E words is 0.
  // If data is int32, odd words are random node ids (mostly nonzero).
  if (i < E && w[2*i+1] != 0u) atomicOr(flag, 1);
}

__global__ __launch_bounds__(256) void k_decode(const void* __restrict__ ei, int E,
                                                const int* __restrict__ flag,
                                                int* __restrict__ src, int* __restrict__ dst){
  int i = blockIdx.x*256 + threadIdx.x;
  if (i >= E) return;
  if (*flag){ // int32
    const int* p = (const int*)ei;
    src[i] = p[i]; dst[i] = p[E+i];
  } else {    // int64
    const long long* p = (const long long*)ei;
    src[i] = (int)p[i]; dst[i] = (int)p[E+i];
  }
}

// ---------------- CSR build by destination ----------------
__global__ __launch_bounds__(256) void k_hist(const int* __restrict__ dst, int E,
                                              int* __restrict__ cnt){
  int i = blockIdx.x*256 + threadIdx.x;
  if (i < E) atomicAdd(&cnt[dst[i]], 1);
}

__global__ __launch_bounds__(256) void k_scan1(const int* __restrict__ cnt, int* __restrict__ rowptr,
                                               int* __restrict__ bsum, int N){
  __shared__ int s[256];
  int tid = threadIdx.x;
  int base = blockIdx.x*1024 + tid*4;
  int v0=0,v1=0,v2=0,v3=0;
  if (base+0 < N) v0 = cnt[base+0];
  if (base+1 < N) v1 = cnt[base+1];
  if (base+2 < N) v2 = cnt[base+2];
  if (base+3 < N) v3 = cnt[base+3];
  s[tid] = v0+v1+v2+v3;
  __syncthreads();
  for (int offd=1; offd<256; offd<<=1){
    int t = (tid>=offd) ? s[tid-offd] : 0;
    __syncthreads();
    s[tid] += t;
    __syncthreads();
  }
  int run = (tid>0) ? s[tid-1] : 0;
  run += v0; if (base+0 < N) rowptr[base+1] = run;
  run += v1; if (base+1 < N) rowptr[base+2] = run;
  run += v2; if (base+2 < N) rowptr[base+3] = run;
  run += v3; if (base+3 < N) rowptr[base+4] = run;
  if (tid==255) bsum[blockIdx.x] = s[255];
}

__global__ void k_scan2(int* __restrict__ bsum, int nb){
  if (threadIdx.x==0 && blockIdx.x==0){
    int acc=0;
    for (int i=0;i<nb;i++){ int t=bsum[i]; bsum[i]=acc; acc+=t; }
  }
}

__global__ __launch_bounds__(256) void k_scan3(int* __restrict__ rowptr, const int* __restrict__ bsum,
                                               int N){
  int tid = threadIdx.x;
  int base = blockIdx.x*1024 + tid*4;
  int add = bsum[blockIdx.x];
  #pragma unroll
  for (int j=0;j<4;j++){ int idx = base+j; if (idx < N) rowptr[idx+1] += add; }
  if (blockIdx.x==0 && tid==0) rowptr[0] = 0;
}

__global__ __launch_bounds__(256) void k_scatter(const int* __restrict__ src, const int* __restrict__ dst,
                                                 int E, const int* __restrict__ rowptr,
                                                 int* __restrict__ fill, int* __restrict__ csr_src){
  int i = blockIdx.x*256 + threadIdx.x;
  if (i >= E) return;
  int d = dst[i];
  int pos = rowptr[d] + atomicAdd(&fill[d], 1);
  csr_src[pos] = src[i];
}

// ---------------- fp32 tiled GEMM: C[M,256] = A[M,256] @ B[256,256] ----------------
#define GBM 128
#define GBN 64
#define GBK 16
__global__ __launch_bounds__(256) void k_gemm1(const float* __restrict__ A, const float* __restrict__ B,
                                               float* __restrict__ C, int M){
  __shared__ float As[GBK][GBM+4];   // transposed: As[k][m]
  __shared__ float Bs[GBK][GBN];
  const int K = 256, NCOL = 256;
  int bm = blockIdx.x * GBM;
  int bn = blockIdx.y * GBN;
  int tid = threadIdx.x;
  int tm = tid >> 4;    // 0..15, owns 8 rows
  int tn = tid & 15;    // 0..15, owns 4 cols
  float acc[8][4];
  #pragma unroll
  for (int i=0;i<8;i++)
    #pragma unroll
    for (int j=0;j<4;j++) acc[i][j] = 0.f;

  for (int k0 = 0; k0 < K; k0 += GBK){
    // A tile: 128 rows x 16 k = 512 float4, 2 per thread
    #pragma unroll
    for (int f = tid; f < (GBM*GBK/4); f += 256){
      int row = f >> 2;
      int kk  = (f & 3) << 2;
      int gr  = bm + row;
      float4 v = make_float4(0.f,0.f,0.f,0.f);
      if (gr < M) v = *(const float4*)&A[(size_t)gr*K + k0 + kk];
      As[kk+0][row] = v.x; As[kk+1][row] = v.y; As[kk+2][row] = v.z; As[kk+3][row] = v.w;
    }
    // B tile: 16 k x 64 cols = 256 float4, 1 per thread
    {
      int row = tid >> 4;
      int col = (tid & 15) << 2;
      float4 v = *(const float4*)&B[(size_t)(k0+row)*NCOL + bn + col];
      *(float4*)&Bs[row][col] = v;
    }
    __syncthreads();
    #pragma unroll
    for (int kk = 0; kk < GBK; ++kk){
      float a[8], b[4];
      *(float4*)&a[0] = *(const float4*)&As[kk][tm*8];
      *(float4*)&a[4] = *(const float4*)&As[kk][tm*8+4];
      *(float4*)&b[0] = *(const float4*)&Bs[kk][tn*4];
      #pragma unroll
      for (int i=0;i<8;i++)
        #pragma unroll
        for (int j=0;j<4;j++)
          acc[i][j] = fmaf(a[i], b[j], acc[i][j]);
    }
    __syncthreads();
  }
  #pragma unroll
  for (int i=0;i<8;i++){
    int gr = bm + tm*8 + i;
    if (gr < M){
      float4 v = make_float4(acc[i][0],acc[i][1],acc[i][2],acc[i][3]);
      *(float4*)&C[(size_t)gr*NCOL + bn + tn*4] = v;
    }
  }
}

// ---------------- per-node attention dot products: alpha_s/alpha_d [N][4] ----------------
__global__ __launch_bounds__(256) void k_alphas(const float* __restrict__ xw,
                                                const float* __restrict__ a_src, const float* __restrict__ a_dst,
                                                float* __restrict__ as1, float* __restrict__ ad1, int N){
  int wave = threadIdx.x >> 6, lane = threadIdx.x & 63;
  int n = blockIdx.x*4 + wave;
  if (n >= N) return;
  float4 v  = *(const float4*)&xw[(size_t)n*256 + lane*4];
  float4 sa = *(const float4*)&a_src[lane*4];
  float4 da = *(const float4*)&a_dst[lane*4];
  float ds = v.x*sa.x + v.y*sa.y + v.z*sa.z + v.w*sa.w;
  float dd = v.x*da.x + v.y*da.y + v.z*da.z + v.w*da.w;
  // reduce within each 16-lane head group
  ds += __shfl_xor(ds, 1);  dd += __shfl_xor(dd, 1);
  ds += __shfl_xor(ds, 2);  dd += __shfl_xor(dd, 2);
  ds += __shfl_xor(ds, 4);  dd += __shfl_xor(dd, 4);
  ds += __shfl_xor(ds, 8);  dd += __shfl_xor(dd, 8);
  if ((lane & 15) == 0){
    int h = lane >> 4;
    as1[n*4 + h] = ds;
    ad1[n*4 + h] = dd;
  }
}

// ---------------- layer-1 aggregation: one wave per destination node ----------------
__global__ __launch_bounds__(256) void k_agg1(const int* __restrict__ rowptr, const int* __restrict__ csr_src,
                                              const float* __restrict__ as1, const float* __restrict__ ad1,
                                              const float* __restrict__ xw, const float* __restrict__ b1,
                                              float* __restrict__ hout, int N){
  int wave = threadIdx.x >> 6, lane = threadIdx.x & 63;
  int n = blockIdx.x*4 + wave;
  if (n >= N) return;
  int hd = lane >> 4;                       // head of this lane's 4 features
  float4 adv = *(const float4*)&ad1[n*4];
  float4 asv = *(const float4*)&as1[n*4];
  float ad_h = pick4(adv, hd);
  float e_self = leaky(pick4(asv, hd) + ad_h);
  int r0 = __builtin_amdgcn_readfirstlane(rowptr[n]);
  int r1 = __builtin_amdgcn_readfirstlane(rowptr[n+1]);
  // pass A: segment max (self loop included)
  float m = e_self;
  for (int i = r0; i < r1; ++i){
    int s = csr_src[i];
    float4 av = *(const float4*)&as1[s*4];
    m = fmaxf(m, leaky(pick4(av, hd) + ad_h));
  }
  // pass B: accumulate sum(p * xw[src]) and sum(p)
  float p = __expf(e_self - m);
  float denom = p;
  float4 v = *(const float4*)&xw[(size_t)n*256 + lane*4];
  float4 acc; acc.x = p*v.x; acc.y = p*v.y; acc.z = p*v.z; acc.w = p*v.w;
  for (int i = r0; i < r1; ++i){
    int s = csr_src[i];
    float4 av = *(const float4*)&as1[s*4];
    float e = leaky(pick4(av, hd) + ad_h);
    float pe = __expf(e - m);
    denom += pe;
    float4 wv = *(const float4*)&xw[(size_t)s*256 + lane*4];
    acc.x = fmaf(pe, wv.x, acc.x);
    acc.y = fmaf(pe, wv.y, acc.y);
    acc.z = fmaf(pe, wv.z, acc.z);
    acc.w = fmaf(pe, wv.w, acc.w);
  }
  float inv = 1.0f / (denom + 1e-16f);
  float4 bv = *(const float4*)&b1[lane*4];
  float4 o;
  o.x = fmaxf(fmaf(acc.x, inv, bv.x), 0.f);
  o.y = fmaxf(fmaf(acc.y, inv, bv.y), 0.f);
  o.z = fmaxf(fmaf(acc.z, inv, bv.z), 0.f);
  o.w = fmaxf(fmaf(acc.w, inv, bv.w), 0.f);
  *(float4*)&hout[(size_t)n*256 + lane*4] = o;
}

// ---------------- layer-2 projection: z[n] = dot(h[n], w2) ----------------
__global__ __launch_bounds__(256) void k_gemv(const float* __restrict__ h, const float* __restrict__ w2,
                                              float* __restrict__ z, int N){
  int wave = threadIdx.x >> 6, lane = threadIdx.x & 63;
  int n = blockIdx.x*4 + wave;
  if (n >= N) return;
  float4 v = *(const float4*)&h[(size_t)n*256 + lane*4];
  float4 w = *(const float4*)&w2[lane*4];
  float d = v.x*w.x + v.y*w.y + v.z*w.z + v.w*w.w;
  d += __shfl_xor(d, 1);
  d += __shfl_xor(d, 2);
  d += __shfl_xor(d, 4);
  d += __shfl_xor(d, 8);
  d += __shfl_xor(d, 16);
  d += __shfl_xor(d, 32);
  if (lane == 0) z[n] = d;
}

// ---------------- layer-2 aggregation (H=F=1): one wave per node, lanes over edges ----------------
__global__ __launch_bounds__(256) void k_agg2(const int* __restrict__ rowptr, const int* __restrict__ csr_src,
                                              const float* __restrict__ z,
                                              const float* __restrict__ as2p, const float* __restrict__ ad2p,
                                              const float* __restrict__ b2p,
                                              float* __restrict__ out, int N){
  int wave = threadIdx.x >> 6, lane = threadIdx.x & 63;
  int n = blockIdx.x*4 + wave;
  if (n >= N) return;
  float cas = as2p[0], cad = ad2p[0], cb = b2p[0];
  float zn = z[n];
  float adn = cad * zn;
  float e_self = leaky(cas*zn + adn);
  int r0 = __builtin_amdgcn_readfirstlane(rowptr[n]);
  int r1 = __builtin_amdgcn_readfirstlane(rowptr[n+1]);
  float m = e_self;
  for (int i = r0 + lane; i < r1; i += 64){
    int s = csr_src[i];
    m = fmaxf(m, leaky(cas*z[s] + adn));
  }
  m = fmaxf(m, __shfl_xor(m, 1));
  m = fmaxf(m, __shfl_xor(m, 2));
  m = fmaxf(m, __shfl_xor(m, 4));
  m = fmaxf(m, __shfl_xor(m, 8));
  m = fmaxf(m, __shfl_xor(m, 16));
  m = fmaxf(m, __shfl_xor(m, 32));
  float num = 0.f, den = 0.f;
  if (lane == 0){
    float p = __expf(e_self - m);
    den = p; num = p * zn;
  }
  for (int i = r0 + lane; i < r1; i += 64){
    int s = csr_src[i];
    float zs = z[s];
    float e = leaky(cas*zs + adn);
    float p = __expf(e - m);
    den += p;
    num = fmaf(p, zs, num);
  }
  num += __shfl_xor(num, 1);  den += __shfl_xor(den, 1);
  num += __shfl_xor(num, 2);  den += __shfl_xor(den, 2);
  num += __shfl_xor(num, 4);  den += __shfl_xor(den, 4);
  num += __shfl_xor(num, 8);  den += __shfl_xor(den, 8);
  num += __shfl_xor(num, 16); den += __shfl_xor(den, 16);
  num += __shfl_xor(num, 32); den += __shfl_xor(den, 32);
  if (lane == 0) out[n] = num / (den + 1e-16f) + cb;
}

// ---------------- launch ----------------
extern "C" void kernel_launch(void* const* d_in, const int* in_sizes, int n_in,
                              void* d_out, int out_size, void* d_ws, size_t ws_size,
                              hipStream_t stream){
  const float* x    = (const float*)d_in[0];
  const void*  ei   = d_in[1];
  const float* w1   = (const float*)d_in[2];
  const float* asw1 = (const float*)d_in[3];
  const float* adw1 = (const float*)d_in[4];
  const float* b1   = (const float*)d_in[5];
  const float* w2   = (const float*)d_in[6];
  const float* as2  = (const float*)d_in[7];
  const float* ad2  = (const float*)d_in[8];
  const float* b2   = (const float*)d_in[9];
  const int N = in_sizes[0] / 256;
  const int E = in_sizes[1] / 2;
  float* out = (float*)d_out;

  char* wsb = (char*)d_ws;
  size_t off = 0;
  auto alloc = [&](size_t bytes) -> void* {
    void* p = wsb + off;
    off = (off + bytes + 255) & ~(size_t)255;
    return p;
  };
  int*   flag    = (int*)  alloc(4);
  int*   src     = (int*)  alloc((size_t)E*4);
  int*   dst     = (int*)  alloc((size_t)E*4);
  int*   cnt     = (int*)  alloc((size_t)N*4);
  int*   fill    = (int*)  alloc((size_t)N*4);
  int*   rowptr  = (int*)  alloc((size_t)(N+1)*4);
  int*   bsum    = (int*)  alloc(1024*4);
  int*   csr_src = (int*)  alloc((size_t)E*4);
  float* xw      = (float*)alloc((size_t)N*256*4);
  float* as1     = (float*)alloc((size_t)N*4*4);
  float* ad1     = (float*)alloc((size_t)N*4*4);
  float* hbuf    = (float*)alloc((size_t)N*256*4);
  float* z       = (float*)alloc((size_t)N*4);

  hipMemsetAsync(flag, 0, 4, stream);
  hipMemsetAsync(cnt,  0, (size_t)N*4, stream);
  hipMemsetAsync(fill, 0, (size_t)N*4, stream);

  int gE = (E + 255) / 256;
  k_detect <<<gE, 256, 0, stream>>>((const unsigned int*)ei, E, flag);
  k_decode <<<gE, 256, 0, stream>>>(ei, E, flag, src, dst);
  k_hist   <<<gE, 256, 0, stream>>>(dst, E, cnt);
  int nb = (N + 1023) / 1024;
  k_scan1  <<<nb, 256, 0, stream>>>(cnt, rowptr, bsum, N);
  k_scan2  <<<1, 64, 0, stream>>>(bsum, nb);
  k_scan3  <<<nb, 256, 0, stream>>>(rowptr, bsum, N);
  k_scatter<<<gE, 256, 0, stream>>>(src, dst, E, rowptr, fill, csr_src);

  dim3 gG((N + GBM - 1) / GBM, 256 / GBN);
  k_gemm1  <<<gG, 256, 0, stream>>>(x, w1, xw, N);

  int gN4 = (N + 3) / 4;
  k_alphas <<<gN4, 256, 0, stream>>>(xw, asw1, adw1, as1, ad1, N);
  k_agg1   <<<gN4, 256, 0, stream>>>(rowptr, csr_src, as1, ad1, xw, b1, hbuf, N);
  k_gemv   <<<gN4, 256, 0, stream>>>(hbuf, w2, z, N);
  k_agg2   <<<gN4, 256, 0, stream>>>(rowptr, csr_src, z, as2, ad2, b2, out, N);
}

// Round 2
// 378.395 us; speedup vs baseline: 1.3668x; 1.3668x over previous
//
#include <hip/hip_runtime.h>
#include <cstdint>
#include <cstddef>

#define NEG_SLOPE 0.2f

static __device__ __forceinline__ float leaky(float x){ return x > 0.f ? x : NEG_SLOPE*x; }
static __device__ __forceinline__ float pick4(float4 v, int h){
  float r = v.x;
  if (h==1) r = v.y;
  if (h==2) r = v.z;
  if (h==3) r = v.w;
  return r;
}

// ---------------- edge index decode (int32 vs int64 runtime detection) ----------------
// Single block samples 2048 odd 32-bit words spread across the first 2E words
// (valid range under BOTH interpretations). int64 data (ids < 2^31): odd words
// are all-zero high halves. int32 data: odd words are uniform node ids — 2048
// all-zero samples is impossible in practice. No global atomics.
__global__ __launch_bounds__(256) void k_detect(const unsigned int* __restrict__ w, int E,
                                                int* __restrict__ flag){
  __shared__ int s;
  if (threadIdx.x == 0) s = 0;
  __syncthreads();
  int nz = 0;
  long long total = 2LL * E;           // 32-bit words safely addressable
  #pragma unroll
  for (int j = 0; j < 8; ++j){
    long long idx = ((long long)(threadIdx.x * 8 + j) * total) / 2048;
    idx |= 1;                          // odd word
    if (idx < total) nz |= (w[idx] != 0u);
  }
  if (__any(nz) && (threadIdx.x & 63) == 0) atomicOr(&s, 1);  // LDS atomic, per-wave
  __syncthreads();
  if (threadIdx.x == 0) *flag = s;     // 1 => int32, 0 => int64
}

__global__ __launch_bounds__(256) void k_decode(const void* __restrict__ ei, int E,
                                                const int* __restrict__ flag,
                                                int* __restrict__ src, int* __restrict__ dst){
  int i = blockIdx.x*256 + threadIdx.x;
  if (i >= E) return;
  if (*flag){ // int32
    const int* p = (const int*)ei;
    src[i] = p[i]; dst[i] = p[E+i];
  } else {    // int64
    const long long* p = (const long long*)ei;
    src[i] = (int)p[i]; dst[i] = (int)p[E+i];
  }
}

// ---------------- CSR build by destination ----------------
__global__ __launch_bounds__(256) void k_hist(const int* __restrict__ dst, int E,
                                              int* __restrict__ cnt){
  int i = blockIdx.x*256 + threadIdx.x;
  if (i < E) atomicAdd(&cnt[dst[i]], 1);
}

__global__ __launch_bounds__(256) void k_scan1(const int* __restrict__ cnt, int* __restrict__ rowptr,
                                               int* __restrict__ bsum, int N){
  __shared__ int s[256];
  int tid = threadIdx.x;
  int base = blockIdx.x*1024 + tid*4;
  int v0=0,v1=0,v2=0,v3=0;
  if (base+0 < N) v0 = cnt[base+0];
  if (base+1 < N) v1 = cnt[base+1];
  if (base+2 < N) v2 = cnt[base+2];
  if (base+3 < N) v3 = cnt[base+3];
  s[tid] = v0+v1+v2+v3;
  __syncthreads();
  for (int offd=1; offd<256; offd<<=1){
    int t = (tid>=offd) ? s[tid-offd] : 0;
    __syncthreads();
    s[tid] += t;
    __syncthreads();
  }
  int run = (tid>0) ? s[tid-1] : 0;
  run += v0; if (base+0 < N) rowptr[base+1] = run;
  run += v1; if (base+1 < N) rowptr[base+2] = run;
  run += v2; if (base+2 < N) rowptr[base+3] = run;
  run += v3; if (base+3 < N) rowptr[base+4] = run;
  if (tid==255) bsum[blockIdx.x] = s[255];
}

__global__ void k_scan2(int* __restrict__ bsum, int nb){
  if (threadIdx.x==0 && blockIdx.x==0){
    int acc=0;
    for (int i=0;i<nb;i++){ int t=bsum[i]; bsum[i]=acc; acc+=t; }
  }
}

__global__ __launch_bounds__(256) void k_scan3(int* __restrict__ rowptr, const int* __restrict__ bsum,
                                               int N){
  int tid = threadIdx.x;
  int base = blockIdx.x*1024 + tid*4;
  int add = bsum[blockIdx.x];
  #pragma unroll
  for (int j=0;j<4;j++){ int idx = base+j; if (idx < N) rowptr[idx+1] += add; }
  if (blockIdx.x==0 && tid==0) rowptr[0] = 0;
}

__global__ __launch_bounds__(256) void k_scatter(const int* __restrict__ src, const int* __restrict__ dst,
                                                 int E, const int* __restrict__ rowptr,
                                                 int* __restrict__ fill, int* __restrict__ csr_src){
  int i = blockIdx.x*256 + threadIdx.x;
  if (i >= E) return;
  int d = dst[i];
  int pos = rowptr[d] + atomicAdd(&fill[d], 1);
  csr_src[pos] = src[i];
}

// ---------------- fp32 tiled GEMM: C[M,256] = A[M,256] @ B[256,256] ----------------
#define GBM 128
#define GBN 64
#define GBK 16
__global__ __launch_bounds__(256) void k_gemm1(const float* __restrict__ A, const float* __restrict__ B,
                                               float* __restrict__ C, int M){
  __shared__ float As[GBK][GBM+4];   // transposed: As[k][m]
  __shared__ float Bs[GBK][GBN];
  const int K = 256, NCOL = 256;
  int bm = blockIdx.x * GBM;
  int bn = blockIdx.y * GBN;
  int tid = threadIdx.x;
  int tm = tid >> 4;    // 0..15, owns 8 rows
  int tn = tid & 15;    // 0..15, owns 4 cols
  float acc[8][4];
  #pragma unroll
  for (int i=0;i<8;i++)
    #pragma unroll
    for (int j=0;j<4;j++) acc[i][j] = 0.f;

  for (int k0 = 0; k0 < K; k0 += GBK){
    // A tile: 128 rows x 16 k = 512 float4, 2 per thread
    #pragma unroll
    for (int f = tid; f < (GBM*GBK/4); f += 256){
      int row = f >> 2;
      int kk  = (f & 3) << 2;
      int gr  = bm + row;
      float4 v = make_float4(0.f,0.f,0.f,0.f);
      if (gr < M) v = *(const float4*)&A[(size_t)gr*K + k0 + kk];
      As[kk+0][row] = v.x; As[kk+1][row] = v.y; As[kk+2][row] = v.z; As[kk+3][row] = v.w;
    }
    // B tile: 16 k x 64 cols = 256 float4, 1 per thread
    {
      int row = tid >> 4;
      int col = (tid & 15) << 2;
      float4 v = *(const float4*)&B[(size_t)(k0+row)*NCOL + bn + col];
      *(float4*)&Bs[row][col] = v;
    }
    __syncthreads();
    #pragma unroll
    for (int kk = 0; kk < GBK; ++kk){
      float a[8], b[4];
      *(float4*)&a[0] = *(const float4*)&As[kk][tm*8];
      *(float4*)&a[4] = *(const float4*)&As[kk][tm*8+4];
      *(float4*)&b[0] = *(const float4*)&Bs[kk][tn*4];
      #pragma unroll
      for (int i=0;i<8;i++)
        #pragma unroll
        for (int j=0;j<4;j++)
          acc[i][j] = fmaf(a[i], b[j], acc[i][j]);
    }
    __syncthreads();
  }
  #pragma unroll
  for (int i=0;i<8;i++){
    int gr = bm + tm*8 + i;
    if (gr < M){
      float4 v = make_float4(acc[i][0],acc[i][1],acc[i][2],acc[i][3]);
      *(float4*)&C[(size_t)gr*NCOL + bn + tn*4] = v;
    }
  }
}

// ---------------- per-node attention dot products: alpha_s/alpha_d [N][4] ----------------
__global__ __launch_bounds__(256) void k_alphas(const float* __restrict__ xw,
                                                const float* __restrict__ a_src, const float* __restrict__ a_dst,
                                                float* __restrict__ as1, float* __restrict__ ad1, int N){
  int wave = threadIdx.x >> 6, lane = threadIdx.x & 63;
  int n = blockIdx.x*4 + wave;
  if (n >= N) return;
  float4 v  = *(const float4*)&xw[(size_t)n*256 + lane*4];
  float4 sa = *(const float4*)&a_src[lane*4];
  float4 da = *(const float4*)&a_dst[lane*4];
  float ds = v.x*sa.x + v.y*sa.y + v.z*sa.z + v.w*sa.w;
  float dd = v.x*da.x + v.y*da.y + v.z*da.z + v.w*da.w;
  // reduce within each 16-lane head group
  ds += __shfl_xor(ds, 1);  dd += __shfl_xor(dd, 1);
  ds += __shfl_xor(ds, 2);  dd += __shfl_xor(dd, 2);
  ds += __shfl_xor(ds, 4);  dd += __shfl_xor(dd, 4);
  ds += __shfl_xor(ds, 8);  dd += __shfl_xor(dd, 8);
  if ((lane & 15) == 0){
    int h = lane >> 4;
    as1[n*4 + h] = ds;
    ad1[n*4 + h] = dd;
  }
}

// ---------------- layer-1 aggregation: one wave per destination node ----------------
__global__ __launch_bounds__(256) void k_agg1(const int* __restrict__ rowptr, const int* __restrict__ csr_src,
                                              const float* __restrict__ as1, const float* __restrict__ ad1,
                                              const float* __restrict__ xw, const float* __restrict__ b1,
                                              float* __restrict__ hout, int N){
  int wave = threadIdx.x >> 6, lane = threadIdx.x & 63;
  int n = blockIdx.x*4 + wave;
  if (n >= N) return;
  int hd = lane >> 4;                       // head of this lane's 4 features
  float4 adv = *(const float4*)&ad1[n*4];
  float4 asv = *(const float4*)&as1[n*4];
  float ad_h = pick4(adv, hd);
  float e_self = leaky(pick4(asv, hd) + ad_h);
  int r0 = __builtin_amdgcn_readfirstlane(rowptr[n]);
  int r1 = __builtin_amdgcn_readfirstlane(rowptr[n+1]);
  // pass A: segment max (self loop included)
  float m = e_self;
  for (int i = r0; i < r1; ++i){
    int s = csr_src[i];
    float4 av = *(const float4*)&as1[s*4];
    m = fmaxf(m, leaky(pick4(av, hd) + ad_h));
  }
  // pass B: accumulate sum(p * xw[src]) and sum(p)
  float p = __expf(e_self - m);
  float denom = p;
  float4 v = *(const float4*)&xw[(size_t)n*256 + lane*4];
  float4 acc; acc.x = p*v.x; acc.y = p*v.y; acc.z = p*v.z; acc.w = p*v.w;
  for (int i = r0; i < r1; ++i){
    int s = csr_src[i];
    float4 av = *(const float4*)&as1[s*4];
    float e = leaky(pick4(av, hd) + ad_h);
    float pe = __expf(e - m);
    denom += pe;
    float4 wv = *(const float4*)&xw[(size_t)s*256 + lane*4];
    acc.x = fmaf(pe, wv.x, acc.x);
    acc.y = fmaf(pe, wv.y, acc.y);
    acc.z = fmaf(pe, wv.z, acc.z);
    acc.w = fmaf(pe, wv.w, acc.w);
  }
  float inv = 1.0f / (denom + 1e-16f);
  float4 bv = *(const float4*)&b1[lane*4];
  float4 o;
  o.x = fmaxf(fmaf(acc.x, inv, bv.x), 0.f);
  o.y = fmaxf(fmaf(acc.y, inv, bv.y), 0.f);
  o.z = fmaxf(fmaf(acc.z, inv, bv.z), 0.f);
  o.w = fmaxf(fmaf(acc.w, inv, bv.w), 0.f);
  *(float4*)&hout[(size_t)n*256 + lane*4] = o;
}

// ---------------- layer-2 projection: z[n] = dot(h[n], w2) ----------------
__global__ __launch_bounds__(256) void k_gemv(const float* __restrict__ h, const float* __restrict__ w2,
                                              float* __restrict__ z, int N){
  int wave = threadIdx.x >> 6, lane = threadIdx.x & 63;
  int n = blockIdx.x*4 + wave;
  if (n >= N) return;
  float4 v = *(const float4*)&h[(size_t)n*256 + lane*4];
  float4 w = *(const float4*)&w2[lane*4];
  float d = v.x*w.x + v.y*w.y + v.z*w.z + v.w*w.w;
  d += __shfl_xor(d, 1);
  d += __shfl_xor(d, 2);
  d += __shfl_xor(d, 4);
  d += __shfl_xor(d, 8);
  d += __shfl_xor(d, 16);
  d += __shfl_xor(d, 32);
  if (lane == 0) z[n] = d;
}

// ---------------- layer-2 aggregation (H=F=1): one wave per node, lanes over edges ----------------
__global__ __launch_bounds__(256) void k_agg2(const int* __restrict__ rowptr, const int* __restrict__ csr_src,
                                              const float* __restrict__ z,
                                              const float* __restrict__ as2p, const float* __restrict__ ad2p,
                                              const float* __restrict__ b2p,
                                              float* __restrict__ out, int N){
  int wave = threadIdx.x >> 6, lane = threadIdx.x & 63;
  int n = blockIdx.x*4 + wave;
  if (n >= N) return;
  float cas = as2p[0], cad = ad2p[0], cb = b2p[0];
  float zn = z[n];
  float adn = cad * zn;
  float e_self = leaky(cas*zn + adn);
  int r0 = __builtin_amdgcn_readfirstlane(rowptr[n]);
  int r1 = __builtin_amdgcn_readfirstlane(rowptr[n+1]);
  float m = e_self;
  for (int i = r0 + lane; i < r1; i += 64){
    int s = csr_src[i];
    m = fmaxf(m, leaky(cas*z[s] + adn));
  }
  m = fmaxf(m, __shfl_xor(m, 1));
  m = fmaxf(m, __shfl_xor(m, 2));
  m = fmaxf(m, __shfl_xor(m, 4));
  m = fmaxf(m, __shfl_xor(m, 8));
  m = fmaxf(m, __shfl_xor(m, 16));
  m = fmaxf(m, __shfl_xor(m, 32));
  float num = 0.f, den = 0.f;
  if (lane == 0){
    float p = __expf(e_self - m);
    den = p; num = p * zn;
  }
  for (int i = r0 + lane; i < r1; i += 64){
    int s = csr_src[i];
    float zs = z[s];
    float e = leaky(cas*zs + adn);
    float p = __expf(e - m);
    den += p;
    num = fmaf(p, zs, num);
  }
  num += __shfl_xor(num, 1);  den += __shfl_xor(den, 1);
  num += __shfl_xor(num, 2);  den += __shfl_xor(den, 2);
  num += __shfl_xor(num, 4);  den += __shfl_xor(den, 4);
  num += __shfl_xor(num, 8);  den += __shfl_xor(den, 8);
  num += __shfl_xor(num, 16); den += __shfl_xor(den, 16);
  num += __shfl_xor(num, 32); den += __shfl_xor(den, 32);
  if (lane == 0) out[n] = num / (den + 1e-16f) + cb;
}

// ---------------- launch ----------------
extern "C" void kernel_launch(void* const* d_in, const int* in_sizes, int n_in,
                              void* d_out, int out_size, void* d_ws, size_t ws_size,
                              hipStream_t stream){
  const float* x    = (const float*)d_in[0];
  const void*  ei   = d_in[1];
  const float* w1   = (const float*)d_in[2];
  const float* asw1 = (const float*)d_in[3];
  const float* adw1 = (const float*)d_in[4];
  const float* b1   = (const float*)d_in[5];
  const float* w2   = (const float*)d_in[6];
  const float* as2  = (const float*)d_in[7];
  const float* ad2  = (const float*)d_in[8];
  const float* b2   = (const float*)d_in[9];
  const int N = in_sizes[0] / 256;
  const int E = in_sizes[1] / 2;
  float* out = (float*)d_out;

  char* wsb = (char*)d_ws;
  size_t off = 0;
  auto alloc = [&](size_t bytes) -> void* {
    void* p = wsb + off;
    off = (off + bytes + 255) & ~(size_t)255;
    return p;
  };
  int*   flag    = (int*)  alloc(4);
  int*   src     = (int*)  alloc((size_t)E*4);
  int*   dst     = (int*)  alloc((size_t)E*4);
  int*   cnt     = (int*)  alloc((size_t)N*4);
  int*   fill    = (int*)  alloc((size_t)N*4);
  int*   rowptr  = (int*)  alloc((size_t)(N+1)*4);
  int*   bsum    = (int*)  alloc(1024*4);
  int*   csr_src = (int*)  alloc((size_t)E*4);
  float* xw      = (float*)alloc((size_t)N*256*4);
  float* as1     = (float*)alloc((size_t)N*4*4);
  float* ad1     = (float*)alloc((size_t)N*4*4);
  float* hbuf    = (float*)alloc((size_t)N*256*4);
  float* z       = (float*)alloc((size_t)N*4);

  hipMemsetAsync(cnt,  0, (size_t)N*4, stream);
  hipMemsetAsync(fill, 0, (size_t)N*4, stream);

  int gE = (E + 255) / 256;
  k_detect <<<1, 256, 0, stream>>>((const unsigned int*)ei, E, flag);
  k_decode <<<gE, 256, 0, stream>>>(ei, E, flag, src, dst);
  k_hist   <<<gE, 256, 0, stream>>>(dst, E, cnt);
  int nb = (N + 1023) / 1024;
  k_scan1  <<<nb, 256, 0, stream>>>(cnt, rowptr, bsum, N);
  k_scan2  <<<1, 64, 0, stream>>>(bsum, nb);
  k_scan3  <<<nb, 256, 0, stream>>>(rowptr, bsum, N);
  k_scatter<<<gE, 256, 0, stream>>>(src, dst, E, rowptr, fill, csr_src);

  dim3 gG((N + GBM - 1) / GBM, 256 / GBN);
  k_gemm1  <<<gG, 256, 0, stream>>>(x, w1, xw, N);

  int gN4 = (N + 3) / 4;
  k_alphas <<<gN4, 256, 0, stream>>>(xw, asw1, adw1, as1, ad1, N);
  k_agg1   <<<gN4, 256, 0, stream>>>(rowptr, csr_src, as1, ad1, xw, b1, hbuf, N);
  k_gemv   <<<gN4, 256, 0, stream>>>(hbuf, w2, z, N);
  k_agg2   <<<gN4, 256, 0, stream>>>(rowptr, csr_src, z, as2, ad2, b2, out, N);
}